// Round 14
// baseline (4746.093 us; speedup 1.0000x reference)
//
#include <hip/hip_runtime.h>
#include <cmath>

#define kB 256
#define kS 512
#define kI 128
#define kH 256

typedef __attribute__((ext_vector_type(8))) short short8;
typedef __attribute__((ext_vector_type(4))) short short4v;
typedef __attribute__((ext_vector_type(4))) float f32x4;
typedef unsigned long long u64;

#define AS_STRIDE 408  // bf16 elems; row stride 816B (even 8/bank-group spread)
#define GSTR 18        // g_scr/r_scr row stride in floats (<=2-way banks = free)

// ws: hx u64[2 parity][16 grp][16 b][256 hh] = 1 MiB.
//   u64 = (seq16 << 48) | (hi << 32) | (mid << 16) | lo   (producer-packed split)
#define WS_HX_U64 (2 * 16 * 16 * 256)

__device__ __forceinline__ float sigmoidf_(float z) { return 1.0f / (1.0f + expf(-z)); }

__device__ __forceinline__ unsigned short f2b(float f) {
  unsigned u = __builtin_bit_cast(unsigned, f);
  unsigned r = (u + 0x7fffu + ((u >> 16) & 1u)) >> 16;
  return (unsigned short)r;
}
__device__ __forceinline__ float b2f(unsigned short s) {
  unsigned u = ((unsigned)s) << 16;
  return __builtin_bit_cast(float, u);
}
__device__ __forceinline__ void bsplit2(float f, unsigned short& h_, unsigned short& l_) {
  h_ = f2b(f);
  l_ = f2b(f - b2f(h_));
}
__device__ __forceinline__ void bsplit3(float f, unsigned short& h_, unsigned short& m_, unsigned short& l_) {
  h_ = f2b(f);
  float r1 = f - b2f(h_);
  m_ = f2b(r1);
  l_ = f2b(r1 - b2f(m_));
}

// Coalesced transposed poll of 8 rows at one column; batched stale-retry.
__device__ __forceinline__ void pollrow8(const u64* grp, int col, int rbase,
                                         unsigned seq16, u64* u) {
  unsigned miss = 0xffu;
  for (;;) {
    unsigned nm = 0;
#pragma unroll
    for (int j = 0; j < 8; ++j)
      if (miss & (1u << j))
        u[j] = __hip_atomic_load(grp + (size_t)(rbase + j) * 256 + col,
                                 __ATOMIC_RELAXED, __HIP_MEMORY_SCOPE_SYSTEM);
#pragma unroll
    for (int j = 0; j < 8; ++j)
      if ((miss & (1u << j)) && (unsigned)(u[j] >> 48) != seq16) nm |= 1u << j;
    if (!nm) return;
    miss = nm;
    __builtin_amdgcn_s_sleep(1);
  }
}

// 8-wave block (512 thr), group = 8 blocks (straggler domain 8).
// Split-K waves: wave w = (gate g=w&3, khalf kh=w>>2); each wave computes BOTH
// 16-hh subtiles over its k-range -> each A-fragment ds_read feeds 12 MFMAs
// (2x fewer LDS reads than one-tile-per-wave). Partials summed in the cell.
// amdgpu_waves_per_eu(2,2): 2 waves/SIMD -> 256-VGPR budget -> weights stay
// register-resident (r13's 128-VGPR choice spilled them to scratch).
__global__ void __launch_bounds__(512)
__attribute__((amdgpu_waves_per_eu(2, 2)))
lstm_mfma(const float* __restrict__ x,
          const float* __restrict__ enc_Wx, const float* __restrict__ enc_bx,
          const float* __restrict__ enc_Wh, const float* __restrict__ enc_bh,
          const float* __restrict__ enc_b,
          const float* __restrict__ dec_Wx, const float* __restrict__ dec_bx,
          const float* __restrict__ dec_Wh, const float* __restrict__ dec_bh,
          const float* __restrict__ dec_b,
          const float* __restrict__ rec_W, const float* __restrict__ rec_b,
          float* __restrict__ out,
          u64* __restrict__ hx) {
  __shared__ __align__(16) short As_h[16 * AS_STRIDE];
  __shared__ __align__(16) short As_m[16 * AS_STRIDE];
  __shared__ __align__(16) short As_l[16 * AS_STRIDE];
  __shared__ float g_scr[16 * 16 * GSTR];   // 16 partial tiles (kh,g,st)
  __shared__ float r_scr[16 * 16 * GSTR];   // 16 partial tiles (w,st)
  __shared__ float red[16][32];
  __shared__ float maskS[16];

  const int tid = threadIdx.x;
  const int bt = blockIdx.x & 15;   // b-group (16 rows)
  const int ht = blockIdx.x >> 4;   // hh-slice (0..7, 32 hh each)
  const int b0 = bt << 4, hh0 = ht << 5;
  const int w  = tid >> 6;          // wave: gate g=w&3, khalf kh=w>>2
  const int g  = w & 3;
  const int kh = w >> 2;
  const int l  = tid & 63;
  const int fr = l & 15;            // MFMA frag row/col
  const int gq = l >> 4;            // MFMA k-subgroup
  const int cb = tid >> 5;          // cell: local b row (0..15)
  const int cq = tid & 31;          // cell: hh-local (0..31)
  const int hhc = hh0 + cq;
  const int col  = tid & 255;       // staging: column
  const int rbase = (tid >> 8) * 8; // staging: 8-row half

  // ---- combined biases (per cell thread) ----
  float be0 = enc_bx[0*kH+hhc] + enc_bh[0*kH+hhc] + enc_b[0*kH+hhc];
  float be1 = enc_bx[1*kH+hhc] + enc_bh[1*kH+hhc] + enc_b[1*kH+hhc];
  float be2 = enc_bx[2*kH+hhc] + enc_bh[2*kH+hhc] + enc_b[2*kH+hhc];
  float be3 = enc_bx[3*kH+hhc] + enc_bh[3*kH+hhc] + enc_b[3*kH+hhc];
  float bd0 = dec_bx[0*kH+hhc] + dec_bh[0*kH+hhc] + dec_b[0*kH+hhc];
  float bd1 = dec_bx[1*kH+hhc] + dec_bh[1*kH+hhc] + dec_b[1*kH+hhc];
  float bd2 = dec_bx[2*kH+hhc] + dec_bh[2*kH+hhc] + dec_b[2*kH+hhc];
  float bd3 = dec_bx[3*kH+hhc] + dec_bh[3*kH+hhc] + dec_b[3*kH+hhc];
  float recb = (ht < 4) ? rec_b[ht * 32 + cq] : 0.0f;
  float creg = 0.0f;

  // ---- encoder weights: wave (g,kh) x 2 subtiles x 6 ksteps, 3-way split ----
  short8 wfh[2][6], wfm[2][6], wfl[2][6];
#pragma unroll
  for (int st = 0; st < 2; ++st)
#pragma unroll
  for (int kl = 0; kl < 6; ++kl) {
    int k = (kh * 6 + kl) * 32 + gq * 8;
    const int hw = hh0 + st * 16 + fr;
    const float* src = (k < 128)
        ? (enc_Wx + ((size_t)(g * kH) + hw) * kI + k)
        : (enc_Wh + ((size_t)(g * kH) + hw) * kH + (k - 128));
    short8 hi, mi, lo;
#pragma unroll
    for (int j = 0; j < 8; ++j) {
      unsigned short h_, m_, l_;
      bsplit3(src[j], h_, m_, l_);
      hi[j] = (short)h_; mi[j] = (short)m_; lo[j] = (short)l_;
    }
    wfh[st][kl] = hi; wfm[st][kl] = mi; wfl[st][kl] = lo;
  }

  // ================= encoder: 512 steps =================
  for (int s = 0; s < kS; ++s) {
    const int par = s & 1;
    // stage x: 512 threads x 4 floats (row tid>>5, cols (tid&31)*4..+3)
    {
      const int xb = tid >> 5, xc = (tid & 31) * 4;
      const float* xp = x + ((size_t)(b0 + xb) * kS + s) * kI + xc;
      float4 xv = *(const float4*)xp;
      float arr[4] = {xv.x, xv.y, xv.z, xv.w};
      short4v hv, mv, lv;
      float ss = 0.f;
#pragma unroll
      for (int j = 0; j < 4; ++j) {
        float v = arr[j];
        ss += v * v;
        unsigned short h_, m_, l_;
        bsplit3(v, h_, m_, l_);
        hv[j] = (short)h_; mv[j] = (short)m_; lv[j] = (short)l_;
      }
      *(short4v*)(As_h + xb * AS_STRIDE + xc) = hv;
      *(short4v*)(As_m + xb * AS_STRIDE + xc) = mv;
      *(short4v*)(As_l + xb * AS_STRIDE + xc) = lv;
      red[xb][tid & 31] = ss;
    }
    // stage h: coalesced poll of producer-packed splits (8 rows per thread)
    {
      const u64* grp = hx + ((size_t)(par * 16 + bt) * 16) * 256;
      u64 u[8];
      pollrow8(grp, col, rbase, (unsigned)(s & 0xffff), u);
#pragma unroll
      for (int j = 0; j < 8; ++j) {
        As_h[(rbase + j) * AS_STRIDE + 128 + col] = (short)(unsigned short)(u[j] >> 32);
        As_m[(rbase + j) * AS_STRIDE + 128 + col] = (short)(unsigned short)(u[j] >> 16);
        As_l[(rbase + j) * AS_STRIDE + 128 + col] = (short)(unsigned short)(u[j]);
      }
    }
    __syncthreads();  // B
    if (tid < 16) {
      float ss = 0.f;
#pragma unroll
      for (int j = 0; j < 32; ++j) ss += red[tid][j];
      maskS[tid] = (ss > 1e-6f) ? 1.0f : 0.0f;
    }
    // gate GEMM: k-range [kh*6, kh*6+6), both subtiles share each A-read
    f32x4 acc[2][6];
#pragma unroll
    for (int st = 0; st < 2; ++st)
#pragma unroll
    for (int i = 0; i < 6; ++i) acc[st][i] = (f32x4){0.f, 0.f, 0.f, 0.f};
#pragma unroll
    for (int kl = 0; kl < 6; ++kl) {
      const int ko = (kh * 6 + kl) * 32 + gq * 8;
      const short8 ah = *(const short8*)(As_h + fr * AS_STRIDE + ko);
      const short8 am = *(const short8*)(As_m + fr * AS_STRIDE + ko);
      const short8 al = *(const short8*)(As_l + fr * AS_STRIDE + ko);
#pragma unroll
      for (int st = 0; st < 2; ++st) {
        acc[st][0] = __builtin_amdgcn_mfma_f32_16x16x32_bf16(ah, wfh[st][kl], acc[st][0], 0, 0, 0);
        acc[st][1] = __builtin_amdgcn_mfma_f32_16x16x32_bf16(ah, wfm[st][kl], acc[st][1], 0, 0, 0);
        acc[st][2] = __builtin_amdgcn_mfma_f32_16x16x32_bf16(am, wfh[st][kl], acc[st][2], 0, 0, 0);
        acc[st][3] = __builtin_amdgcn_mfma_f32_16x16x32_bf16(ah, wfl[st][kl], acc[st][3], 0, 0, 0);
        acc[st][4] = __builtin_amdgcn_mfma_f32_16x16x32_bf16(am, wfm[st][kl], acc[st][4], 0, 0, 0);
        acc[st][5] = __builtin_amdgcn_mfma_f32_16x16x32_bf16(al, wfh[st][kl], acc[st][5], 0, 0, 0);
      }
    }
#pragma unroll
    for (int st = 0; st < 2; ++st) {
      f32x4 d = (((acc[st][5] + acc[st][4]) + acc[st][3]) + (acc[st][2] + acc[st][1])) + acc[st][0];
      const int ti = (kh * 4 + g) * 2 + st;
#pragma unroll
      for (int i = 0; i < 4; ++i) g_scr[(ti * 16 + gq * 4 + i) * GSTR + fr] = d[i];
    }
    __syncthreads();  // C
    // cell update: sum the two khalf partials per gate
    {
      const int st = cq >> 4, fq = cq & 15;
      float gf = g_scr[(((0*4+0)*2+st)*16+cb)*GSTR+fq] + g_scr[(((1*4+0)*2+st)*16+cb)*GSTR+fq] + be0;
      float gi = g_scr[(((0*4+1)*2+st)*16+cb)*GSTR+fq] + g_scr[(((1*4+1)*2+st)*16+cb)*GSTR+fq] + be1;
      float go = g_scr[(((0*4+2)*2+st)*16+cb)*GSTR+fq] + g_scr[(((1*4+2)*2+st)*16+cb)*GSTR+fq] + be2;
      float gc = g_scr[(((0*4+3)*2+st)*16+cb)*GSTR+fq] + g_scr[(((1*4+3)*2+st)*16+cb)*GSTR+fq] + be3;
      float m  = maskS[cb];
      float f_ = sigmoidf_(gf), i_ = sigmoidf_(gi), o_ = sigmoidf_(go);
      float ct = tanhf(gc);
      creg = (f_ + i_) * creg + m * (i_ * ct);
      float hval = o_ * tanhf(creg);
      unsigned short hb, mb2, lb;
      bsplit3(hval, hb, mb2, lb);
      u64 pk = ((u64)(unsigned)((s + 1) & 0xffff) << 48) | ((u64)hb << 32) | ((u64)mb2 << 16) | (u64)lb;
      size_t wi = (((size_t)(((s + 1) & 1) * 16 + bt) * 16 + cb) * 256) + hhc;
      __hip_atomic_store(hx + wi, pk, __ATOMIC_RELAXED, __HIP_MEMORY_SCOPE_SYSTEM);
    }
  }

  // ---- decoder weights: wdc = dec_Wx + dec_Wh; wave (g,kh) x 2 st x 4 ksteps ----
  short8 dwh[2][4], dwm[2][4], dwl[2][4];
#pragma unroll
  for (int st = 0; st < 2; ++st)
#pragma unroll
  for (int kl = 0; kl < 4; ++kl) {
    int k = (kh * 4 + kl) * 32 + gq * 8;
    const int hw = hh0 + st * 16 + fr;
    const float* s1 = dec_Wx + ((size_t)(g * kH) + hw) * kH + k;
    const float* s2 = dec_Wh + ((size_t)(g * kH) + hw) * kH + k;
    short8 hi, mi, lo;
#pragma unroll
    for (int j = 0; j < 8; ++j) {
      unsigned short h_, m_, l_;
      bsplit3(s1[j] + s2[j], h_, m_, l_);
      hi[j] = (short)h_; mi[j] = (short)m_; lo[j] = (short)l_;
    }
    dwh[st][kl] = hi; dwm[st][kl] = mi; dwl[st][kl] = lo;
  }
  // rec weights (ht<4): wave w -> rec kstep w; both 16-col subtiles
  short8 rfh[2], rfl[2];
#pragma unroll
  for (int st = 0; st < 2; ++st) {
    short8 hi = {0,0,0,0,0,0,0,0}, lo = hi;
    if (ht < 4) {
      int k = w * 32 + gq * 8;
      const float* src = rec_W + ((size_t)(ht * 32 + st * 16 + fr)) * kH + k;
#pragma unroll
      for (int j = 0; j < 8; ++j) {
        unsigned short h_, l_;
        bsplit2(src[j], h_, l_);
        hi[j] = (short)h_; lo[j] = (short)l_;
      }
    }
    rfh[st] = hi; rfl[st] = lo;
  }

  // ================= decoder: 512 steps =================
  for (int t = 0; t < kS; ++t) {
    const int s = kS + t;
    const int par = s & 1;
    // stage h coalesced (col offset 0)
    {
      const u64* grp = hx + ((size_t)(par * 16 + bt) * 16) * 256;
      u64 u[8];
      pollrow8(grp, col, rbase, (unsigned)(s & 0xffff), u);
#pragma unroll
      for (int j = 0; j < 8; ++j) {
        As_h[(rbase + j) * AS_STRIDE + col] = (short)(unsigned short)(u[j] >> 32);
        As_m[(rbase + j) * AS_STRIDE + col] = (short)(unsigned short)(u[j] >> 16);
        As_l[(rbase + j) * AS_STRIDE + col] = (short)(unsigned short)(u[j]);
      }
    }
    __syncthreads();  // B1
    // silence-mask partials from LDS reconstruction
    if (tid < 256) {
      const int mb = tid >> 4, mq = tid & 15;
      float ss = 0.f;
#pragma unroll
      for (int g2 = 0; g2 < 2; ++g2) {
        const short8 hv = *(const short8*)(As_h + mb * AS_STRIDE + mq * 16 + g2 * 8);
        const short8 mv = *(const short8*)(As_m + mb * AS_STRIDE + mq * 16 + g2 * 8);
        const short8 lv = *(const short8*)(As_l + mb * AS_STRIDE + mq * 16 + g2 * 8);
#pragma unroll
        for (int j = 0; j < 8; ++j) {
          float v = b2f((unsigned short)hv[j]) + b2f((unsigned short)mv[j]) + b2f((unsigned short)lv[j]);
          ss += v * v;
        }
      }
      red[mb][mq] = ss;
    }
    __syncthreads();  // B2
    if (tid < 16) {
      float ss = 0.f;
#pragma unroll
      for (int j = 0; j < 16; ++j) ss += red[tid][j];
      maskS[tid] = (ss > 1e-6f) ? 1.0f : 0.0f;
    }
    // gate GEMM: k-range [kh*4, kh*4+4), both subtiles share each A-read
    f32x4 acc[2][6];
#pragma unroll
    for (int st = 0; st < 2; ++st)
#pragma unroll
    for (int i = 0; i < 6; ++i) acc[st][i] = (f32x4){0.f, 0.f, 0.f, 0.f};
#pragma unroll
    for (int kl = 0; kl < 4; ++kl) {
      const int ko = (kh * 4 + kl) * 32 + gq * 8;
      const short8 ah = *(const short8*)(As_h + fr * AS_STRIDE + ko);
      const short8 am = *(const short8*)(As_m + fr * AS_STRIDE + ko);
      const short8 al = *(const short8*)(As_l + fr * AS_STRIDE + ko);
#pragma unroll
      for (int st = 0; st < 2; ++st) {
        acc[st][0] = __builtin_amdgcn_mfma_f32_16x16x32_bf16(ah, dwh[st][kl], acc[st][0], 0, 0, 0);
        acc[st][1] = __builtin_amdgcn_mfma_f32_16x16x32_bf16(ah, dwm[st][kl], acc[st][1], 0, 0, 0);
        acc[st][2] = __builtin_amdgcn_mfma_f32_16x16x32_bf16(am, dwh[st][kl], acc[st][2], 0, 0, 0);
        acc[st][3] = __builtin_amdgcn_mfma_f32_16x16x32_bf16(ah, dwl[st][kl], acc[st][3], 0, 0, 0);
        acc[st][4] = __builtin_amdgcn_mfma_f32_16x16x32_bf16(am, dwm[st][kl], acc[st][4], 0, 0, 0);
        acc[st][5] = __builtin_amdgcn_mfma_f32_16x16x32_bf16(al, dwh[st][kl], acc[st][5], 0, 0, 0);
      }
    }
#pragma unroll
    for (int st = 0; st < 2; ++st) {
      f32x4 d = (((acc[st][5] + acc[st][4]) + acc[st][3]) + (acc[st][2] + acc[st][1])) + acc[st][0];
      const int ti = (kh * 4 + g) * 2 + st;
#pragma unroll
      for (int i = 0; i < 4; ++i) g_scr[(ti * 16 + gq * 4 + i) * GSTR + fr] = d[i];
    }
    // rec GEMM: wave w does rec kstep w for both col-subtiles
    if (ht < 4) {
      const int ko = w * 32 + gq * 8;
      const short8 ah = *(const short8*)(As_h + fr * AS_STRIDE + ko);
      const short8 am = *(const short8*)(As_m + fr * AS_STRIDE + ko);
#pragma unroll
      for (int st = 0; st < 2; ++st) {
        f32x4 r0 = {0.f,0.f,0.f,0.f}, r1 = r0, r2 = r0;
        r0 = __builtin_amdgcn_mfma_f32_16x16x32_bf16(ah, rfh[st], r0, 0, 0, 0);
        r1 = __builtin_amdgcn_mfma_f32_16x16x32_bf16(ah, rfl[st], r1, 0, 0, 0);
        r2 = __builtin_amdgcn_mfma_f32_16x16x32_bf16(am, rfh[st], r2, 0, 0, 0);
        f32x4 rd = r0 + r1 + r2;
#pragma unroll
        for (int i = 0; i < 4; ++i) r_scr[((w * 2 + st) * 16 + gq * 4 + i) * GSTR + fr] = rd[i];
      }
    }
    __syncthreads();  // C
    // cell update + packed-split publish
    {
      const int st = cq >> 4, fq = cq & 15;
      float gf = g_scr[(((0*4+0)*2+st)*16+cb)*GSTR+fq] + g_scr[(((1*4+0)*2+st)*16+cb)*GSTR+fq] + bd0;
      float gi = g_scr[(((0*4+1)*2+st)*16+cb)*GSTR+fq] + g_scr[(((1*4+1)*2+st)*16+cb)*GSTR+fq] + bd1;
      float go = g_scr[(((0*4+2)*2+st)*16+cb)*GSTR+fq] + g_scr[(((1*4+2)*2+st)*16+cb)*GSTR+fq] + bd2;
      float gc = g_scr[(((0*4+3)*2+st)*16+cb)*GSTR+fq] + g_scr[(((1*4+3)*2+st)*16+cb)*GSTR+fq] + bd3;
      float m  = maskS[cb];
      float f_ = sigmoidf_(gf), i_ = sigmoidf_(gi), o_ = sigmoidf_(go);
      float ct = tanhf(gc);
      creg = (f_ + i_) * creg + m * (i_ * ct);
      float hval = o_ * tanhf(creg);
      unsigned short hb, mb2, lb;
      bsplit3(hval, hb, mb2, lb);
      u64 pk = ((u64)(unsigned)((s + 1) & 0xffff) << 48) | ((u64)hb << 32) | ((u64)mb2 << 16) | (u64)lb;
      size_t wi = (((size_t)(((s + 1) & 1) * 16 + bt) * 16 + cb) * 256) + hhc;
      __hip_atomic_store(hx + wi, pk, __ATOMIC_RELAXED, __HIP_MEMORY_SCOPE_SYSTEM);
    }
    // out[:, t-1, :]: sum the 8 rec k-step partials
    if (ht < 4 && t > 0) {
      const int st = cq >> 4, fq = cq & 15;
      float rsum = recb;
#pragma unroll
      for (int ww = 0; ww < 8; ++ww)
        rsum += r_scr[((ww * 2 + st) * 16 + cb) * GSTR + fq];
      __builtin_nontemporal_store(rsum, &out[((size_t)(b0 + cb) * kS + (t - 1)) * kI + ht * 32 + cq]);
    }
  }

  // ================= final rec: out[:, 511, :] =================
  {
    {
      const u64* grp = hx + ((size_t)(0 * 16 + bt) * 16) * 256;
      u64 u[8];
      pollrow8(grp, col, rbase, (unsigned)((2 * kS) & 0xffff), u);
#pragma unroll
      for (int j = 0; j < 8; ++j) {
        As_h[(rbase + j) * AS_STRIDE + col] = (short)(unsigned short)(u[j] >> 32);
        As_m[(rbase + j) * AS_STRIDE + col] = (short)(unsigned short)(u[j] >> 16);
      }
    }
    __syncthreads();
    if (ht < 4) {
      const int ko = w * 32 + gq * 8;
      const short8 ah = *(const short8*)(As_h + fr * AS_STRIDE + ko);
      const short8 am = *(const short8*)(As_m + fr * AS_STRIDE + ko);
#pragma unroll
      for (int st = 0; st < 2; ++st) {
        f32x4 r0 = {0.f,0.f,0.f,0.f}, r1 = r0, r2 = r0;
        r0 = __builtin_amdgcn_mfma_f32_16x16x32_bf16(ah, rfh[st], r0, 0, 0, 0);
        r1 = __builtin_amdgcn_mfma_f32_16x16x32_bf16(ah, rfl[st], r1, 0, 0, 0);
        r2 = __builtin_amdgcn_mfma_f32_16x16x32_bf16(am, rfh[st], r2, 0, 0, 0);
        f32x4 rd = r0 + r1 + r2;
#pragma unroll
        for (int i = 0; i < 4; ++i) r_scr[((w * 2 + st) * 16 + gq * 4 + i) * GSTR + fr] = rd[i];
      }
    }
    __syncthreads();
    if (ht < 4) {
      const int st = cq >> 4, fq = cq & 15;
      float rsum = recb;
#pragma unroll
      for (int ww = 0; ww < 8; ++ww)
        rsum += r_scr[((ww * 2 + st) * 16 + cb) * GSTR + fq];
      __builtin_nontemporal_store(rsum, &out[((size_t)(b0 + cb) * kS + (kS - 1)) * kI + ht * 32 + cq]);
    }
  }
}

extern "C" void kernel_launch(void* const* d_in, const int* in_sizes, int n_in,
                              void* d_out, int out_size, void* d_ws, size_t ws_size,
                              hipStream_t stream) {
  const float* x      = (const float*)d_in[0];
  const float* enc_Wx = (const float*)d_in[1];
  const float* enc_bx = (const float*)d_in[2];
  const float* enc_Wh = (const float*)d_in[3];
  const float* enc_bh = (const float*)d_in[4];
  const float* enc_b  = (const float*)d_in[5];
  const float* dec_Wx = (const float*)d_in[6];
  const float* dec_bx = (const float*)d_in[7];
  const float* dec_Wh = (const float*)d_in[8];
  const float* dec_bh = (const float*)d_in[9];
  const float* dec_b  = (const float*)d_in[10];
  const float* rec_W  = (const float*)d_in[11];
  const float* rec_b  = (const float*)d_in[12];
  float* out = (float*)d_out;

  u64* hx = (u64*)d_ws;

  // zero hx: seq=0 with zero payload == "h_0 = 0 valid" for the first step
  hipMemsetAsync(d_ws, 0, (size_t)WS_HX_U64 * 8, stream);

  hipLaunchKernelGGL(lstm_mfma, dim3(128), dim3(512), 0, stream,
                     x, enc_Wx, enc_bx, enc_Wh, enc_bh, enc_b,
                     dec_Wx, dec_bx, dec_Wh, dec_bh, dec_b,
                     rec_W, rec_b, out, hx);
}